// Round 10
// baseline (2430.861 us; speedup 1.0000x reference)
//
#include <hip/hip_runtime.h>
#include <math.h>

using f16x8 = __attribute__((ext_vector_type(8))) _Float16;
using f32x4 = __attribute__((ext_vector_type(4))) float;
using u32x4 = __attribute__((ext_vector_type(4))) unsigned int;
using u16   = unsigned short;

// ---------------- problem constants ----------------
constexpr int Tst = 60;

// ---------------- workspace: A-fragment streams (layout identical to rounds 4-9) ----
constexpr int FR      = 512;
constexpr int N_AG0   = 64 * 9  * 2 * FR;
constexpr int N_AL0   = 64 * 9  * 2 * FR;
constexpr int N_AL1   = 64 * 17 * 2 * FR;
constexpr int N_AH1   = 4  * 9  * 2 * FR;
constexpr int OFF_AG0 = 0;
constexpr int OFF_AL0 = OFF_AG0 + N_AG0;
constexpr int OFF_AL1 = OFF_AL0 + N_AL0;
constexpr int OFF_AH1 = OFF_AL1 + N_AL1;
constexpr int WS_U16  = OFF_AH1 + N_AH1;          // 2,330,624 u16

// ---------------- h-exchange slabs (16-row groups) + padded flags ----------------
// H[gbc 128][par 2][layer 2] slab of [kt 8][sb 2][512] u16 = 16 KB
constexpr int N_HSLAB = 8 * 2 * 512;              // 8192 u16
constexpr int OFF_H   = WS_U16;
constexpr int N_H     = 128 * 2 * 2 * N_HSLAB;    // 4,194,304 u16
constexpr int OFF_FLG = OFF_H + N_H;
constexpr int FLG_STRIDE = 16;                    // ints (64 B)
constexpr int N_FLAGS_I  = 128 * 2 * 4 * FLG_STRIDE;
constexpr size_t WS_BYTES = (size_t)OFF_FLG * 2 + (size_t)N_FLAGS_I * sizeof(int);

__device__ __forceinline__ u16 hbits(_Float16 h) {
    union { _Float16 h; u16 u; } x; x.h = h; return x.u;
}

// ---------------- weight repack (verbatim — validated rounds 4-9) ----------------
__global__ void prep_kernel(const float* __restrict__ Wih0, const float* __restrict__ Whh0,
                            const float* __restrict__ bih0, const float* __restrict__ bhh0,
                            const float* __restrict__ Wih1, const float* __restrict__ Whh1,
                            const float* __restrict__ bih1, const float* __restrict__ bhh1,
                            const float* __restrict__ Wout1, const float* __restrict__ bout1,
                            u16* __restrict__ ws) {
    int i = blockIdx.x * 256 + threadIdx.x;
    if (i >= WS_U16) return;
    int arr, idx = i, KT;
    if (i < OFF_AL0)      { arr = 0; KT = 9; }
    else if (i < OFF_AL1) { arr = 1; idx -= OFF_AL0; KT = 9; }
    else if (i < OFF_AH1) { arr = 2; idx -= OFF_AL1; KT = 17; }
    else                  { arr = 3; idx -= OFF_AH1; KT = 9; }
    const int per_mt = KT * 2 * FR;
    const int mt = idx / per_mt;
    int r = idx - mt * per_mt;
    const int kt = r / (2 * FR);
    r -= kt * 2 * FR;
    const int s    = r >> 9;
    const int f    = r & 511;
    const int lane = f >> 3, j = f & 7;
    const int m    = mt * 16 + (lane & 15);
    const int k_in = ((lane >> 4) << 3) + j;

    float v = 0.f;
    if (arr == 3) {
        if (kt < 8) v = Wout1[m * 256 + kt * 32 + k_in];
        else if (k_in == 0) v = bout1[m];
    } else {
        const int unit = m >> 2, gate = m & 3, row = gate * 256 + unit;
        if (arr == 0) {
            if (kt < 8) v = Wih0[row * 258 + 2 + kt * 32 + k_in];
            else if (k_in == 0) v = bih0[row] + bhh0[row];
        } else if (arr == 1) {
            if (kt < 8) v = Whh0[row * 256 + kt * 32 + k_in];
            else if (k_in < 2) v = Wih0[row * 258 + k_in];
        } else {
            if (kt < 8)         v = Wih1[row * 256 + kt * 32 + k_in];
            else if (kt < 16)   v = Whh1[row * 256 + (kt - 8) * 32 + k_in];
            else if (k_in == 0) v = bih1[row] + bhh1[row];
        }
    }
    _Float16 hi = (_Float16)v;
    ws[i] = (s == 0) ? hbits(hi) : hbits((_Float16)(v - (float)hi));
}

// ---------------- helpers ----------------
__device__ __forceinline__ f32x4 MF(f16x8 a, f16x8 b, f32x4 c) {
    return __builtin_amdgcn_mfma_f32_16x16x32_f16(a, b, c, 0, 0, 0);
}
__device__ __forceinline__ float sigm(float x) { return 1.f / (1.f + __expf(-x)); }
__device__ __forceinline__ float tanh_(float x) {
    float e = __expf(-2.f * fabsf(x));
    float r = (1.f - e) / (1.f + e);
    return copysignf(r, x);
}
__device__ __forceinline__ float lstm_out(f32x4 g, float& c) {
    float iv = sigm(g[0]), fv = sigm(g[1]), gv = tanh_(g[2]), ov = sigm(g[3]);
    c = fmaf(fv, c, iv * gv);
    return ov * tanh_(c);
}
__device__ __forceinline__ void waitcnt0() {
    asm volatile("s_waitcnt vmcnt(0)" ::: "memory");
}
__device__ __forceinline__ void st16_sc(u16* p, u16 v) {
    asm volatile("global_store_short %0, %1, off sc0 sc1" :: "v"(p), "v"((unsigned)v) : "memory");
}
__device__ __forceinline__ void ld4_sc(const u32x4* p, u32x4& v) {
    asm volatile("global_load_dwordx4 %0, %1, off sc0 sc1" : "=v"(v) : "v"(p));
}
__device__ __forceinline__ void st4_sc(u32x4* p, u32x4 v) {
    asm volatile("global_store_dwordx4 %0, %1, off sc0 sc1" :: "v"(p), "v"(v) : "memory");
}
// 16 KB coherent global->LDS stage; 1024 threads x 16B
__device__ __forceinline__ void stage16k(const u16* g, u16* lds, int t) {
    const u32x4* s = (const u32x4*)g;
    u32x4 v;
    ld4_sc(s + t, v);
    waitcnt0();
    __builtin_amdgcn_sched_barrier(0);
    ((u32x4*)lds)[t] = v;
}
__device__ __forceinline__ void spin_ge(int* p, int target) {
    while (__hip_atomic_load(p, __ATOMIC_RELAXED, __HIP_MEMORY_SCOPE_AGENT) < target)
        __builtin_amdgcn_s_sleep(1);
}
__device__ __forceinline__ size_t hidx(int gbc, int par, int layer) {
    return (size_t)((gbc * 2 + par) * 2 + layer) * N_HSLAB;
}
__device__ __forceinline__ int* fptr(int* flags, int gbc, int layer, int uc) {
    return flags + (size_t)((gbc * 2 + layer) * 4 + uc) * FLG_STRIDE;
}

// ---------------- main kernel: 256 blocks = 64 sbc x 4 uc, 1024 thr = 16 waves ----
// Each block: 2 independent 16-row groups (gbc = sbc*2+g), software-pipelined
// A0,A1,B0,B1,C0,C1 so each group's exchange latency hides under the sibling's compute.
// wave w owns M-tile (uc*16 + w): units [uc*64 + 4w, uc*64 + 4w + 4).
__global__ __launch_bounds__(1024) void lstm_main(
    const float* __restrict__ env, const float* __restrict__ hist,
    const float* __restrict__ goal, const float* __restrict__ cpos,
    const float* __restrict__ Wproj, const float* __restrict__ b_proj,
    const float* __restrict__ Wout2, const float* __restrict__ b_out2,
    u16* __restrict__ wsu, float* __restrict__ out) {

    __shared__ __align__(16) unsigned char smem[82432];
    u16*   X0   = (u16*)smem;                     // 16 KB (retained h1, G0)
    u16*   X1   = (u16*)(smem + 16384);           // 16 KB (retained h1, G1)
    u16*   Y0   = (u16*)(smem + 32768);           // 16 KB (retained h2, G0)
    u16*   Y1   = (u16*)(smem + 49152);           // 16 KB (retained h2, G1)
    u16*   hSt  = (u16*)(smem + 65536);           // 4 KB own-slice coalesce
    float* mlpL = (float*)(smem + 69632);         // [16][68] f32 = 4352 B
    float* part = (float*)(smem + 73984);         // [128] f32
    u16*   posF0= (u16*)(smem + 74496);           // [sb2][512]
    u16*   posF1= (u16*)(smem + 76544);
    u16*   onesF= (u16*)(smem + 78592);           // [sb2][512]
    float* xbuf = (float*)smem;                   // prologue overlay [386][32]
    float* ctxL = (float*)(smem + 49408);         // prologue overlay [256][32]

    const int t   = threadIdx.x;
    const int w   = t >> 6;                       // 0..15
    const int l   = t & 63;
    const int sbc = (int)blockIdx.x >> 2;
    const int uc  = (int)blockIdx.x & 3;          // one uc per XCD -> weights L2-resident
    const int row0 = sbc * 32;

    u16* Hb = wsu + OFF_H;
    int* flags = (int*)(wsu + OFF_FLG);

    const u16* AG0w = wsu + OFF_AG0 + (size_t)(uc * 16 + w) * (9 * 1024)  + l * 8;
    const u16* A0w  = wsu + OFF_AL0 + (size_t)(uc * 16 + w) * (9 * 1024)  + l * 8;
    const u16* A1w  = wsu + OFF_AL1 + (size_t)(uc * 16 + w) * (17 * 1024) + l * 8;
    const u16* AHw  = wsu + OFF_AH1 + (size_t)(w & 3) * (9 * 1024) + l * 8;

    // ---- P1: stage ctx_in [k][r] (32 rows) ----
    for (int idx = t; idx < 386 * 32; idx += 1024) {
        int r = idx & 31, k = idx >> 5;
        int gr = row0 + r; float v;
        if (k < 256)      v = env[gr * 256 + k];
        else if (k < 384) v = hist[gr * 128 + (k - 256)];
        else              v = goal[gr * 2 + (k - 384)];
        xbuf[k * 32 + r] = v;
    }
    __syncthreads();

    // ---- P2: context fp32 ----
    {
        const int u = t & 255, rh = t >> 8;       // rh 0..3
        float acc[8];
        float bp = b_proj[u];
#pragma unroll
        for (int rr = 0; rr < 8; ++rr) acc[rr] = bp;
        for (int k = 0; k < 386; ++k) {
            float wv = Wproj[u * 386 + k];
            const float* xr = &xbuf[k * 32 + rh * 8];
#pragma unroll
            for (int rr = 0; rr < 8; ++rr) acc[rr] = fmaf(xr[rr], wv, acc[rr]);
        }
#pragma unroll
        for (int rr = 0; rr < 8; ++rr) ctxL[u * 32 + rh * 8 + rr] = acc[rr];
    }
    __syncthreads();

    // ---- P3: write own uc-slice of h1(-1), h2(-1) slabs for both groups (parity 1) ----
    for (int idx = t; idx < 8192; idx += 1024) {
        int f = idx & 511, sb = (idx >> 9) & 1, kl = (idx >> 10) & 1;
        int g = (idx >> 11) & 1, layer = idx >> 12;
        int lane = f >> 3, j = f & 7;
        int k_in = ((lane >> 4) << 3) + j;
        int Ug = uc * 64 + kl * 32 + k_in;
        float v = ctxL[Ug * 32 + g * 16 + (lane & 15)];
        _Float16 hi = (_Float16)v;
        u16 val = sb ? hbits((_Float16)(v - (float)hi)) : hbits(hi);
        int kt = uc * 2 + kl;
        st16_sc(Hb + hidx(sbc * 2 + g, 1, layer) + (kt * 2 + sb) * 512 + f, val);
    }
    waitcnt0();
    __syncthreads();
    if (t == 0) {
#pragma unroll
        for (int g = 0; g < 2; ++g)
#pragma unroll
            for (int layer = 0; layer < 2; ++layer)
                __hip_atomic_store(fptr(flags, sbc * 2 + g, layer, uc), 0,
                                   __ATOMIC_RELAXED, __HIP_MEMORY_SCOPE_AGENT);
    }
    __syncthreads();    // ctxL reads done -> overlay region reusable

    // ---- P4: posF (both groups) + onesF ----
    for (int idx = t; idx < 2048; idx += 1024) {
        int f = idx & 511, sb = (idx >> 9) & 1, g = idx >> 10;
        int lane = f >> 3, j = f & 7;
        int k_in = ((lane >> 4) << 3) + j;
        u16 val = 0;
        if (k_in < 2) {
            float pv = cpos[(row0 + g * 16 + (lane & 15)) * 2 + k_in];
            _Float16 hi = (_Float16)pv;
            val = sb ? hbits((_Float16)(pv - (float)hi)) : hbits(hi);
        }
        (g ? posF1 : posF0)[sb * 512 + f] = val;
    }
    {
        int f = t & 511, sb = (t >> 9) & 1;
        if (t < 1024) {
            int lane = f >> 3, j = f & 7;
            int k_in = ((lane >> 4) << 3) + j;
            onesF[sb * 512 + f] = (sb == 0 && k_in == 0) ? hbits((_Float16)1.0f) : (u16)0;
        }
    }
    __syncthreads();

    // ---- P5: stage X,Y for both groups; compute G0c per group ----
    f32x4 G0c[2];
    float c1[2] = {0, 0}, c2[2] = {0, 0};
#pragma unroll
    for (int g = 0; g < 2; ++g) {
        u16* Xg = g ? X1 : X0;
        u16* Yg = g ? Y1 : Y0;
        const int gb = sbc * 2 + g;
        if (t < 4)      spin_ge(fptr(flags, gb, 0, t), 0);
        else if (t < 8) spin_ge(fptr(flags, gb, 1, t - 4), 0);
        __syncthreads();
        stage16k(Hb + hidx(gb, 1, 0), Xg, t);
        stage16k(Hb + hidx(gb, 1, 1), Yg, t);
        __syncthreads();
        f32x4 G = {0, 0, 0, 0};
#pragma unroll
        for (int kt = 0; kt < 8; ++kt) {
            f16x8 bh = *(const f16x8*)&Xg[(kt * 2 + 0) * 512 + l * 8];
            f16x8 bl = *(const f16x8*)&Xg[(kt * 2 + 1) * 512 + l * 8];
            const u16* p = AG0w + kt * 1024;
            f16x8 ah = *(const f16x8*)p, al = *(const f16x8*)(p + 512);
            G = MF(ah, bh, G); G = MF(ah, bl, G); G = MF(al, bh, G);
        }
        {
            f16x8 bh = *(const f16x8*)&onesF[l * 8];
            f16x8 bl = *(const f16x8*)&onesF[512 + l * 8];
            const u16* p = AG0w + 8 * 1024;
            f16x8 ah = *(const f16x8*)p, al = *(const f16x8*)(p + 512);
            G = MF(ah, bh, G); G = MF(ah, bl, G); G = MF(al, bh, G);
        }
        G0c[g] = G;
    }
    __syncthreads();

    // pack constants for h-slice store
    const int U   = w * 4 + (l >> 4);
    const int kl_ = U >> 5, ki = U & 31;
    const int fp_ = ((l & 15) + 16 * (ki >> 3)) * 8 + (ki & 7);

    // ================= time loop =================
    for (int s = 0; s < Tst; ++s) {
        const int par = s & 1;

        // ===== Phase A (x2 groups): L0 local from retained X + posF -> h1(s) =====
#pragma unroll
        for (int g = 0; g < 2; ++g) {
            u16* Xg = g ? X1 : X0;
            u16* posFg = g ? posF1 : posF0;
            const int gb = sbc * 2 + g;
            f32x4 a = G0c[g];
#pragma unroll
            for (int kt = 0; kt < 8; ++kt) {
                f16x8 bh = *(const f16x8*)&Xg[(kt * 2 + 0) * 512 + l * 8];
                f16x8 bl = *(const f16x8*)&Xg[(kt * 2 + 1) * 512 + l * 8];
                const u16* p = A0w + kt * 1024;
                f16x8 ah = *(const f16x8*)p, al = *(const f16x8*)(p + 512);
                a = MF(ah, bh, a); a = MF(ah, bl, a); a = MF(al, bh, a);
            }
            {   // pos column (kt 8)
                f16x8 bh = *(const f16x8*)&posFg[l * 8];
                f16x8 bl = *(const f16x8*)&posFg[512 + l * 8];
                const u16* p = A0w + 8 * 1024;
                f16x8 ah = *(const f16x8*)p, al = *(const f16x8*)(p + 512);
                a = MF(ah, bh, a); a = MF(ah, bl, a); a = MF(al, bh, a);
            }
            float h1n = lstm_out(a, c1[g]);
            _Float16 hi = (_Float16)h1n;
            hSt[(kl_ * 2 + 0) * 512 + fp_] = hbits(hi);
            hSt[(kl_ * 2 + 1) * 512 + fp_] = hbits((_Float16)(h1n - (float)hi));
            __syncthreads();                              // hSt ready (also orders prev use)
            if (t < 256)
                st4_sc((u32x4*)(Hb + hidx(gb, par, 0) + uc * 2048) + t, ((const u32x4*)hSt)[t]);
            waitcnt0();
            __syncthreads();                              // slice stored; hSt reusable
            if (t == 0) __hip_atomic_store(fptr(flags, gb, 0, uc), s + 1,
                                           __ATOMIC_RELAXED, __HIP_MEMORY_SCOPE_AGENT);
        }

        // ===== Phase B (x2 groups): L1 -> h2(s); Y-part first (no deps), then spin+stage X =====
#pragma unroll
        for (int g = 0; g < 2; ++g) {
            u16* Xg = g ? X1 : X0;
            u16* Yg = g ? Y1 : Y0;
            const int gb = sbc * 2 + g;
            f32x4 a = {0, 0, 0, 0};
#pragma unroll
            for (int ks = 0; ks < 8; ++ks) {              // Whh1 @ h2(s-1), retained Y
                f16x8 bh = *(const f16x8*)&Yg[(ks * 2 + 0) * 512 + l * 8];
                f16x8 bl = *(const f16x8*)&Yg[(ks * 2 + 1) * 512 + l * 8];
                const u16* p = A1w + (8 + ks) * 1024;
                f16x8 ah = *(const f16x8*)p, al = *(const f16x8*)(p + 512);
                a = MF(ah, bh, a); a = MF(ah, bl, a); a = MF(al, bh, a);
            }
            {   // bias column (kt 16)
                f16x8 bh = *(const f16x8*)&onesF[l * 8];
                f16x8 bl = *(const f16x8*)&onesF[512 + l * 8];
                const u16* p = A1w + 16 * 1024;
                f16x8 ah = *(const f16x8*)p, al = *(const f16x8*)(p + 512);
                a = MF(ah, bh, a); a = MF(ah, bl, a); a = MF(al, bh, a);
            }
            if (t < 4) spin_ge(fptr(flags, gb, 0, t), s + 1);   // h1(s) full
            __syncthreads();
            stage16k(Hb + hidx(gb, par, 0), Xg, t);       // X <- h1(s), retained for A(s+1)
            __syncthreads();
#pragma unroll
            for (int kt = 0; kt < 8; ++kt) {              // Wih1 @ h1(s)
                f16x8 bh = *(const f16x8*)&Xg[(kt * 2 + 0) * 512 + l * 8];
                f16x8 bl = *(const f16x8*)&Xg[(kt * 2 + 1) * 512 + l * 8];
                const u16* p = A1w + kt * 1024;
                f16x8 ah = *(const f16x8*)p, al = *(const f16x8*)(p + 512);
                a = MF(ah, bh, a); a = MF(ah, bl, a); a = MF(al, bh, a);
            }
            float h2n = lstm_out(a, c2[g]);
            _Float16 hi = (_Float16)h2n;
            hSt[(kl_ * 2 + 0) * 512 + fp_] = hbits(hi);
            hSt[(kl_ * 2 + 1) * 512 + fp_] = hbits((_Float16)(h2n - (float)hi));
            __syncthreads();                              // hSt ready
            if (t < 256)
                st4_sc((u32x4*)(Hb + hidx(gb, par, 1) + uc * 2048) + t, ((const u32x4*)hSt)[t]);
            waitcnt0();
            __syncthreads();                              // slice stored
            if (t == 0) __hip_atomic_store(fptr(flags, gb, 1, uc), s + 1,
                                           __ATOMIC_RELAXED, __HIP_MEMORY_SCOPE_AGENT);
        }

        // ===== Phase C (x2 groups): stage Y = h2(s); head -> out[s], posF(s+1) =====
#pragma unroll
        for (int g = 0; g < 2; ++g) {
            u16* Yg = g ? Y1 : Y0;
            u16* posFg = g ? posF1 : posF0;
            const int gb = sbc * 2 + g;
            if (t < 4) spin_ge(fptr(flags, gb, 1, t), s + 1);   // h2(s) full
            __syncthreads();
            stage16k(Hb + hidx(gb, par, 1), Yg, t);       // Y <- h2(s), retained for B(s+1)
            __syncthreads();
            if (w < 4) {                                  // head MFMA: mlp = relu(h2@Wout1^T+b1)
                f32x4 pv = {0, 0, 0, 0};
#pragma unroll
                for (int kt = 0; kt < 8; ++kt) {
                    f16x8 bh = *(const f16x8*)&Yg[(kt * 2 + 0) * 512 + l * 8];
                    f16x8 bl = *(const f16x8*)&Yg[(kt * 2 + 1) * 512 + l * 8];
                    const u16* p = AHw + kt * 1024;
                    f16x8 ah = *(const f16x8*)p, al = *(const f16x8*)(p + 512);
                    pv = MF(ah, bh, pv); pv = MF(ah, bl, pv); pv = MF(al, bh, pv);
                }
                {
                    f16x8 bh = *(const f16x8*)&onesF[l * 8];
                    f16x8 bl = *(const f16x8*)&onesF[512 + l * 8];
                    const u16* p = AHw + 8 * 1024;
                    f16x8 ah = *(const f16x8*)p, al = *(const f16x8*)(p + 512);
                    pv = MF(ah, bh, pv); pv = MF(ah, bl, pv); pv = MF(al, bh, pv);
                }
#pragma unroll
                for (int r = 0; r < 4; ++r) pv[r] = fmaxf(pv[r], 0.f);
                *(f32x4*)&mlpL[(l & 15) * 68 + w * 16 + (l >> 4) * 4] = pv;
            }
            __syncthreads();                              // mlpL ready
            if (t < 128) {                                // head2 partials: (q4, r16, o2)
                const int q = t >> 5, idx = t & 31, r = idx >> 1, o = idx & 1;
                float a = 0.f;
#pragma unroll
                for (int k = 0; k < 16; ++k)
                    a = fmaf(mlpL[r * 68 + q * 16 + k], Wout2[o * 64 + q * 16 + k], a);
                part[t] = a;
            }
            __syncthreads();
            if (t < 32) {
                const int r = t >> 1, o = t & 1;
                float a = b_out2[o] + part[t] + part[32 + t] + part[64 + t] + part[96 + t];
                if (uc == 0) out[((size_t)(row0 + g * 16 + r) * Tst + s) * 2 + o] = a;
                _Float16 hi = (_Float16)a;
                posFg[r * 8 + o]       = hbits(hi);
                posFg[512 + r * 8 + o] = hbits((_Float16)(a - (float)hi));
            }
            __syncthreads();                              // posF(s+1) ready
        }
    }
}

// ---------------- launch ----------------
extern "C" void kernel_launch(void* const* d_in, const int* in_sizes, int n_in,
                              void* d_out, int out_size, void* d_ws, size_t ws_size,
                              hipStream_t stream) {
    const float* env   = (const float*)d_in[0];
    const float* hist  = (const float*)d_in[1];
    const float* goal  = (const float*)d_in[2];
    const float* cpos  = (const float*)d_in[3];
    const float* Wproj = (const float*)d_in[4];
    const float* bproj = (const float*)d_in[5];
    const float* Wih0  = (const float*)d_in[6];
    const float* Whh0  = (const float*)d_in[7];
    const float* bih0  = (const float*)d_in[8];
    const float* bhh0  = (const float*)d_in[9];
    const float* Wih1  = (const float*)d_in[10];
    const float* Whh1  = (const float*)d_in[11];
    const float* bih1  = (const float*)d_in[12];
    const float* bhh1  = (const float*)d_in[13];
    const float* Wout1 = (const float*)d_in[14];
    const float* bout1 = (const float*)d_in[15];
    const float* Wout2 = (const float*)d_in[16];
    const float* bout2 = (const float*)d_in[17];

    if (ws_size < WS_BYTES) return;
    u16* wsu = (u16*)d_ws;

    (void)hipMemsetAsync((char*)d_ws + (size_t)OFF_FLG * 2, 0xFF,
                         (size_t)N_FLAGS_I * sizeof(int), stream);

    prep_kernel<<<(WS_U16 + 255) / 256, 256, 0, stream>>>(
        Wih0, Whh0, bih0, bhh0, Wih1, Whh1, bih1, bhh1, Wout1, bout1, wsu);

    lstm_main<<<256, 1024, 0, stream>>>(
        env, hist, goal, cpos, Wproj, bproj, Wout2, bout2, wsu, (float*)d_out);
}